// Round 6
// baseline (370.968 us; speedup 1.0000x reference)
//
#include <hip/hip_runtime.h>
#include <math.h>

// LSTM B=1024,T=512,IN=16,H=64,OUT=8, gates i,f,g,o.
// R6: latency-path surgery on R5 (which was 1 wave/SIMD, both pipes <13%
// busy, 1430 cyc/step vs ~550 issue):
//  - fp16 weights/h/x, single product (no hi/lo split): 24->12 MFMAs,
//    h-chain depth 6->2, and MORE accurate (fp16 mantissa 11b > bf16 8b for
//    h/x, the dominant error term in R5's 3.9e-3).
//  - x-term off critical path: during step t compute xacc_{t+1} =
//    mfma(W_ih frag, x_{t+1} frag, bias) (bias in C operand); x loaded
//    global->regs 2 steps ahead, no LDS staging. h-LDS K=64 = 2 chunks.
//  - hbuf row stride 72 halves (36 dwords, 36%32=4): quarter-wave b128
//    banks spread 4m -> 2-way (free); R5's stride 48 dwords gave 16m%32 in
//    {0,16} -> 8-way, 5.28e6 conflict cycles.
// 64 blocks x 256 thr (BT=16 batches/block), tiles tt=gate type, in-lane
// activation (acc[tt][r] = gate tt of j=16w+4q+r, b=mcol). 1 barrier/step.

#define LSTM_T 512
#define LSTM_IN 16
#define LSTM_H 64
#define LSTM_OUT 8
#define BT 16
#define HSTRIDE 72         // halves per batch row: 64 h + 8 pad

#define L2E   1.44269504088896340736f
#define L2E2  2.88539008177792681472f

typedef _Float16 half8  __attribute__((ext_vector_type(8)));
typedef _Float16 half4v __attribute__((ext_vector_type(4)));
typedef float    floatx4 __attribute__((ext_vector_type(4)));

static __device__ __forceinline__ float fast_rcp(float x) { return __builtin_amdgcn_rcpf(x); }
static __device__ __forceinline__ float fast_exp2(float x) { return __builtin_amdgcn_exp2f(x); }
// pre already scaled by log2e:
static __device__ __forceinline__ float sigm2(float p) { return fast_rcp(1.0f + fast_exp2(-p)); }
// pre already scaled by 2*log2e: tanh = 1 - 2/(1+2^pre)
static __device__ __forceinline__ float tanh2(float p) {
    return fmaf(-2.0f, fast_rcp(1.0f + fast_exp2(p)), 1.0f);
}
static __device__ __forceinline__ void pin4(int4& v) {
    asm volatile("" : "+v"(v.x), "+v"(v.y), "+v"(v.z), "+v"(v.w));
}
static __device__ __forceinline__ void pinf4(float4& v) {
    asm volatile("" : "+v"(v.x), "+v"(v.y), "+v"(v.z), "+v"(v.w));
}

static __device__ __forceinline__ half8 to_h8(float4 a, float4 b) {
    half8 h;
    h[0] = (_Float16)a.x; h[1] = (_Float16)a.y; h[2] = (_Float16)a.z; h[3] = (_Float16)a.w;
    h[4] = (_Float16)b.x; h[5] = (_Float16)b.y; h[6] = (_Float16)b.z; h[7] = (_Float16)b.w;
    return h;
}
static __device__ __forceinline__ int4 cvt8h(float4 a, float4 b, float sc) {
    float4 as = make_float4(a.x * sc, a.y * sc, a.z * sc, a.w * sc);
    float4 bs = make_float4(b.x * sc, b.y * sc, b.z * sc, b.w * sc);
    return __builtin_bit_cast(int4, to_h8(as, bs));
}

// one LSTM timestep (inlined twice for ping-pong)
static __device__ __forceinline__ void lstm_step(
    int t, const _Float16* cur, _Float16* nxt,
    floatx4* accIn, floatx4* accOut,            // [4] each
    float4& xc0, float4& xc1,                   // consumed: x_{t+1}
    float4& xl0, float4& xl1,                   // load dest: x_{t+2}
    const float4* bias4, const int4 (*Ah)[2], const int4* Ax,
    float* creg, float* hreg,
    const float* xlanebase, int q, int w, int mcol)
{
    // h B-fragments for step t (written before previous barrier)
    half8 b0 = *reinterpret_cast<const half8*>(cur + mcol * HSTRIDE + 8 * q);
    half8 b1 = *reinterpret_cast<const half8*>(cur + mcol * HSTRIDE + 32 + 8 * q);

    // issue x_{t+2} global load (consumed next step; full step of slack)
    if (q < 2 && t + 2 < LSTM_T) {
        const float* p = xlanebase + (size_t)(t + 2) * LSTM_IN;
        xl0 = *reinterpret_cast<const float4*>(p);
        xl1 = *reinterpret_cast<const float4*>(p + 4);
    }

    // x MFMA for step t+1 (off critical path): accOut = bias + W_ih . x_{t+1}
    // q>=2 lanes: xc regs stay 0 (never written) and Ax rows are 0.
    half8 xf = to_h8(xc0, xc1);
    #pragma unroll
    for (int tt = 0; tt < 4; ++tt)
        accOut[tt] = __builtin_amdgcn_mfma_f32_16x16x32_f16(
            __builtin_bit_cast(half8, Ax[tt]), xf,
            __builtin_bit_cast(floatx4, bias4[tt]), 0, 0, 0);

    // h MFMAs (critical path, depth 2, 4 independent chains), in-place
    #pragma unroll
    for (int tt = 0; tt < 4; ++tt)
        accIn[tt] = __builtin_amdgcn_mfma_f32_16x16x32_f16(
            __builtin_bit_cast(half8, Ah[tt][0]), b0, accIn[tt], 0, 0, 0);
    #pragma unroll
    for (int tt = 0; tt < 4; ++tt)
        accIn[tt] = __builtin_amdgcn_mfma_f32_16x16x32_f16(
            __builtin_bit_cast(half8, Ah[tt][1]), b1, accIn[tt], 0, 0, 0);

    // in-lane activation + state: accIn[tt][r] = gate tt of (j=16w+4q+r, b=mcol)
    half4v hv;
    #pragma unroll
    for (int r = 0; r < 4; ++r) {
        float gi = sigm2(accIn[0][r]);
        float gf = sigm2(accIn[1][r]);
        float gg = tanh2(accIn[2][r]);
        float go = sigm2(accIn[3][r]);
        creg[r] = fmaf(gf, creg[r], gi * gg);
        hreg[r] = go * tanh2(creg[r] * L2E2);
        hv[r] = (_Float16)hreg[r];
    }

    // h_t -> next buffer (8B store; j = 16w+4q..+3 of batch mcol)
    *reinterpret_cast<half4v*>(nxt + mcol * HSTRIDE + 16 * w + 4 * q) = hv;

    __syncthreads();
}

__global__ __launch_bounds__(256, 1)
void lstm_mfma_kernel(const float* __restrict__ x,
                      const float* __restrict__ W_ih,
                      const float* __restrict__ W_hh,
                      const float* __restrict__ b_ih,
                      const float* __restrict__ b_hh,
                      const float* __restrict__ W_fc,
                      const float* __restrict__ b_fc,
                      float* __restrict__ out) {
    const int tid   = threadIdx.x;
    const int lane  = tid & 63;
    const int w     = tid >> 6;       // wave -> j-slice [16w, 16w+16)
    const int q     = lane >> 4;      // k-quad / C row group (j = 16w+4q+r)
    const int mcol  = lane & 15;      // A row-in-tile / B col / C col (batch)
    const int bbase = blockIdx.x * BT;

    __shared__ __align__(16) _Float16 hbuf[2][BT][HSTRIDE];  // h state, dbuf
    __shared__ __align__(16) float hfin[BT][LSTM_H];         // final h for FC

    // ---- weights as pinned fp16 A-fragments, log2e folded ----
    // tile tt = gate type; A row = tt*64 + 16w + mcol.
    // h chunks: k0..63 = W_hh row. x chunk: k0..15 = W_ih row, k16..31 = 0.
    int4 Ah[4][2], Ax[4];
    float4 bias4[4];
    #pragma unroll
    for (int tt = 0; tt < 4; ++tt) {
        const float sc = (tt == 2) ? L2E2 : L2E;
        const int gt = tt * 64 + 16 * w + mcol;
        #pragma unroll
        for (int c = 0; c < 2; ++c) {
            const float* s = W_hh + gt * LSTM_H + 32 * c + 8 * q;
            Ah[tt][c] = cvt8h(*reinterpret_cast<const float4*>(s),
                              *reinterpret_cast<const float4*>(s + 4), sc);
            pin4(Ah[tt][c]);
        }
        float4 xa = make_float4(0.f, 0.f, 0.f, 0.f);
        float4 xb = make_float4(0.f, 0.f, 0.f, 0.f);
        if (q < 2) {
            const float* s = W_ih + gt * LSTM_IN + 8 * q;
            xa = *reinterpret_cast<const float4*>(s);
            xb = *reinterpret_cast<const float4*>(s + 4);
        }
        Ax[tt] = cvt8h(xa, xb, sc);
        pin4(Ax[tt]);
        const int gb = tt * 64 + 16 * w + 4 * q;   // gates for C regs r=0..3
        float4 bi = *reinterpret_cast<const float4*>(b_ih + gb);
        float4 bh = *reinterpret_cast<const float4*>(b_hh + gb);
        bias4[tt] = make_float4((bi.x + bh.x) * sc, (bi.y + bh.y) * sc,
                                (bi.z + bh.z) * sc, (bi.w + bh.w) * sc);
        pinf4(bias4[tt]);
    }

    // ---- zero hbuf (h_{-1} = 0) ----
    {
        int* z = reinterpret_cast<int*>(hbuf);     // 2*16*72 halves = 1152 ints
        #pragma unroll
        for (int k = 0; k < 5; ++k) {
            int i = tid + 256 * k;
            if (i < 1152) z[i] = 0;
        }
    }

    // ---- x pipeline prologue (register-only, overlaps the zeroing) ----
    // lane base: batch mcol, element 8q (q<2 lanes carry real x)
    const float* xlanebase = x + (size_t)(bbase + mcol) * LSTM_T * LSTM_IN + 8 * q;
    float4 xc0 = make_float4(0.f, 0.f, 0.f, 0.f), xc1 = xc0;
    float4 xl0 = xc0, xl1 = xc0;
    if (q < 2) {   // x_0
        xc0 = *reinterpret_cast<const float4*>(xlanebase);
        xc1 = *reinterpret_cast<const float4*>(xlanebase + 4);
    }
    floatx4 xaccA[4], xaccB[4];
    {
        half8 xf0 = to_h8(xc0, xc1);
        #pragma unroll
        for (int tt = 0; tt < 4; ++tt)
            xaccA[tt] = __builtin_amdgcn_mfma_f32_16x16x32_f16(
                __builtin_bit_cast(half8, Ax[tt]), xf0,
                __builtin_bit_cast(floatx4, bias4[tt]), 0, 0, 0);
    }
    if (q < 2) {   // x_1 -> consumed at step 0
        xc0 = *reinterpret_cast<const float4*>(xlanebase + LSTM_IN);
        xc1 = *reinterpret_cast<const float4*>(xlanebase + LSTM_IN + 4);
    }
    __syncthreads();   // hbuf zeros visible

    float creg[4] = {0.f, 0.f, 0.f, 0.f};
    float hreg[4] = {0.f, 0.f, 0.f, 0.f};

    for (int t = 0; t < LSTM_T; t += 2) {
        lstm_step(t,     &hbuf[0][0][0], &hbuf[1][0][0], xaccA, xaccB,
                  xc0, xc1, xl0, xl1, bias4, Ah, Ax, creg, hreg,
                  xlanebase, q, w, mcol);
        lstm_step(t + 1, &hbuf[1][0][0], &hbuf[0][0][0], xaccB, xaccA,
                  xl0, xl1, xc0, xc1, bias4, Ah, Ax, creg, hreg,
                  xlanebase, q, w, mcol);
    }

    // ---- final h (fp32, from regs) -> LDS, then FC + sigmoid ----
    *reinterpret_cast<float4*>(&hfin[mcol][16 * w + 4 * q]) =
        make_float4(hreg[0], hreg[1], hreg[2], hreg[3]);
    __syncthreads();

    if (tid < BT * LSTM_OUT) {
        int b = tid >> 3, o = tid & 7;
        float s = b_fc[o];
        #pragma unroll 8
        for (int j = 0; j < LSTM_H; ++j) s = fmaf(W_fc[o * LSTM_H + j], hfin[b][j], s);
        out[(size_t)(bbase + b) * LSTM_OUT + o] = sigm2(s * L2E);
    }
}

extern "C" void kernel_launch(void* const* d_in, const int* in_sizes, int n_in,
                              void* d_out, int out_size, void* d_ws, size_t ws_size,
                              hipStream_t stream) {
    const float* x    = (const float*)d_in[0];
    const float* W_ih = (const float*)d_in[1];
    const float* W_hh = (const float*)d_in[2];
    const float* b_ih = (const float*)d_in[3];
    const float* b_hh = (const float*)d_in[4];
    const float* W_fc = (const float*)d_in[5];
    const float* b_fc = (const float*)d_in[6];
    float* out = (float*)d_out;

    lstm_mfma_kernel<<<1024 / BT, 256, 0, stream>>>(
        x, W_ih, W_hh, b_ih, b_hh, W_fc, b_fc, out);
}